// Round 2
// 1533.546 us; speedup vs baseline: 1.2496x; 1.2496x over previous
//
#include <hip/hip_runtime.h>

typedef float f4 __attribute__((ext_vector_type(4)));
typedef short s8v __attribute__((ext_vector_type(8)));
typedef unsigned short us4 __attribute__((ext_vector_type(4)));
typedef unsigned long long u64;

#define NEGV -1.0e10f

__device__ __forceinline__ unsigned short f2b(float f) {
    unsigned int u = __builtin_bit_cast(unsigned int, f);
    unsigned int r = u + 0x7fffu + ((u >> 16) & 1u);
    return (unsigned short)(r >> 16);
}

// XOR swizzle for 128B-row LDS tiles (both-sides-or-neither)
__device__ __forceinline__ int swz_a(int row, int cb) {
    return (row * 128 + cb) ^ ((row & 7) << 4);
}
__device__ __forceinline__ void lds_wr16(unsigned short* b, int row, int cb, s8v v) {
    *(s8v*)((char*)b + swz_a(row, cb)) = v;
}
__device__ __forceinline__ s8v lds_rd16(const unsigned short* b, int row, int cb) {
    return *(const s8v*)((const char*)b + swz_a(row, cb));
}

__device__ __forceinline__ void gll16(const void* g, void* l) {
    __builtin_amdgcn_global_load_lds((const __attribute__((address_space(1))) void*)g,
                                     (__attribute__((address_space(3))) void*)l, 16, 0, 0);
}

// ---------------- mask packing: ballot, coalesced ----------------
__global__ __launch_bounds__(256) void pack_mask_kernel(const int* __restrict__ mask,
                                                        unsigned int* __restrict__ bits) {
    int i = blockIdx.x * 256 + threadIdx.x;  // one int per thread, 16.8M total
    u64 b = __ballot(mask[i] != 0);
    if ((threadIdx.x & 63) == 0) *(u64*)(bits + (i >> 5)) = b;
}

// ---------------- fp32 -> bf16 vectorized converts ----------------
__global__ __launch_bounds__(256) void cvt_w_kernel(
    const float* __restrict__ w0, const float* __restrict__ w1,
    const float* __restrict__ w2, const float* __restrict__ w3,
    unsigned short* __restrict__ o0, unsigned short* __restrict__ o1,
    unsigned short* __restrict__ o2, unsigned short* __restrict__ o3) {
    const float* src;
    unsigned short* dst;
    switch (blockIdx.y) {
        case 0: src = w0; dst = o0; break;
        case 1: src = w1; dst = o1; break;
        case 2: src = w2; dst = o2; break;
        default: src = w3; dst = o3; break;
    }
    int i = (blockIdx.x * blockDim.x + threadIdx.x) * 4;
    f4 v = *(const f4*)(src + i);
    us4 t;
    t.x = f2b(v.x); t.y = f2b(v.y); t.z = f2b(v.z); t.w = f2b(v.w);
    *(us4*)&dst[i] = t;
}

__global__ __launch_bounds__(256) void cvt_a_kernel(const float* __restrict__ src,
                                                    unsigned short* __restrict__ dst) {
    int i = (blockIdx.x * 256 + threadIdx.x) * 4;
    f4 v = *(const f4*)(src + i);
    us4 t;
    t.x = f2b(v.x); t.y = f2b(v.y); t.z = f2b(v.z); t.w = f2b(v.w);
    *(us4*)&dst[i] = t;
}

// ---------------- GEMM m97-structure: C[M,N] = A[M,K] @ W[N,K]^T + bias ----------------
// A bf16. OUTM==0: bf16 out [B,NH,S,HD] * scale; OUTM==1: fp32 flat [M,N];
// OUTM==2: bf16 out transposed [B,NH,HD,S] (for V)
template <int OUTM>
__global__ __launch_bounds__(256) void gemm_kernel(const unsigned short* __restrict__ A,
                                                   const unsigned short* __restrict__ Bw,
                                                   const float* __restrict__ bias,
                                                   void* __restrict__ Outp, float scale) {
    constexpr int K = 1024;
    __shared__ unsigned short As[128 * 32];
    __shared__ unsigned short Bs[128 * 32];
    const int tid = threadIdx.x;
    const int lane = tid & 63;
    const int wv = tid >> 6;
    const int wrow = (wv >> 1) * 64, wcol = (wv & 1) * 64;
    const int fr = lane & 15, fq = lane >> 4;
    const int bm = blockIdx.x * 128, bn = blockIdx.y * 128;

    f4 zero = {0.f, 0.f, 0.f, 0.f};
    f4 acc[4][4];
#pragma unroll
    for (int a = 0; a < 4; a++)
#pragma unroll
        for (int b2 = 0; b2 < 4; b2++) acc[a][b2] = zero;

    for (int k0 = 0; k0 < K; k0 += 32) {
        // global -> LDS direct, 16B/lane, linear LDS (gll writes wave-uniform base + lane*16)
#pragma unroll
        for (int c = 0; c < 2; c++) {
            int off = wv * 2048 + c * 1024 + lane * 16;  // byte offset within 8KB tile
            int row = off >> 6;                          // 64B per row (32 bf16)
            int col = (off & 63) >> 1;                   // shorts
            gll16(A + (size_t)(bm + row) * K + k0 + col, (char*)As + wv * 2048 + c * 1024);
            gll16(Bw + (size_t)(bn + row) * K + k0 + col, (char*)Bs + wv * 2048 + c * 1024);
        }
        __syncthreads();  // drains vmcnt(0): gll complete
        s8v af[4], bf[4];
#pragma unroll
        for (int rt = 0; rt < 4; rt++) af[rt] = *(const s8v*)&As[(wrow + rt * 16 + fr) * 32 + fq * 8];
#pragma unroll
        for (int ct = 0; ct < 4; ct++) bf[ct] = *(const s8v*)&Bs[(wcol + ct * 16 + fr) * 32 + fq * 8];
#pragma unroll
        for (int rt = 0; rt < 4; rt++)
#pragma unroll
            for (int ct = 0; ct < 4; ct++)
                acc[rt][ct] = __builtin_amdgcn_mfma_f32_16x16x32_bf16(af[rt], bf[ct], acc[rt][ct], 0, 0, 0);
        __syncthreads();
    }
#pragma unroll
    for (int rt = 0; rt < 4; rt++) {
#pragma unroll
        for (int ct = 0; ct < 4; ct++) {
            int j = bn + wcol + ct * 16 + fr;
            float bj = bias[j];
#pragma unroll
            for (int r = 0; r < 4; r++) {
                int i = bm + wrow + rt * 16 + fq * 4 + r;
                float v = (acc[rt][ct][r] + bj) * scale;
                if (OUTM == 0) {
                    int batch = i >> 11, s = i & 2047, hh = j >> 6, d = j & 63;
                    ((unsigned short*)Outp)[(((size_t)(batch * 16 + hh) * 2048 + s) * 64) + d] = f2b(v);
                } else if (OUTM == 1) {
                    ((float*)Outp)[(size_t)i * 1024 + j] = v;
                } else {
                    int batch = i >> 11, s = i & 2047, hh = j >> 6, d = j & 63;
                    ((unsigned short*)Outp)[(((size_t)(batch * 16 + hh) * 64 + d) * 2048) + s] = f2b(v);
                }
            }
        }
    }
}

// ---------------- fused two-pass attention, per (qtile64, head, batch) ----------------
// V input pre-transposed: vth is [B,NH,HD,S]. Double-buffered K/V tiles, 1 barrier/iter.
__global__ __launch_bounds__(256) void attn_kernel(const unsigned short* __restrict__ qh,
                                                   const unsigned short* __restrict__ kh,
                                                   const unsigned short* __restrict__ vth,
                                                   const unsigned int* __restrict__ mbits,
                                                   float* __restrict__ attn,
                                                   unsigned short* __restrict__ xh) {
    const int S = 2048;
    const int qt = blockIdx.x, hh = blockIdx.y, bb = blockIdx.z;
    const int tid = threadIdx.x, lane = tid & 63, wv = tid >> 6;
    const int fr = lane & 15, fq = lane >> 4;
    __shared__ unsigned short kT[2][64 * 64];  // [k][d], XOR-swizzled, double-buffered
    __shared__ unsigned short vT[2][64 * 64];  // [d][k], XOR-swizzled, double-buffered
    __shared__ unsigned short pS[64 * 64];     // [q][k], per-wave private rows
    size_t hoff = ((size_t)(bb * 16 + hh)) * S * 64;
    const unsigned short* q = qh + hoff;
    const unsigned short* k = kh + hoff;
    const unsigned short* vt = vth + hoff;  // row stride S (d-major)
    const int srow = tid >> 2;
    const int scb = (tid & 3) * 32;  // byte col of first 16B chunk
    const int scs = scb >> 1;        // in shorts

    // ---- Q tile -> LDS (borrow pS) -> persistent A-frags ----
    {
        const unsigned short* src = q + (size_t)(qt * 64 + srow) * 64 + scs;
        lds_wr16(pS, srow, scb, *(const s8v*)src);
        lds_wr16(pS, srow, scb + 16, *(const s8v*)(src + 8));
    }
    __syncthreads();
    s8v aq0 = lds_rd16(pS, wv * 16 + fr, fq * 16);
    s8v aq1 = lds_rd16(pS, wv * 16 + fr, 64 + fq * 16);
    // no barrier needed: pS next written in pass 2, many barriers away

    const int sqbase = qt * 64 + wv * 16 + fq * 4;
    const int rowbase = (bb * 2048 + sqbase) * 64;  // mask u32-word index of row sqbase
    float m0[4], l0[4];
#pragma unroll
    for (int r = 0; r < 4; r++) { m0[r] = -__builtin_huge_valf(); l0[r] = 0.f; }

    // ---- pass 1: row max + sumexp ----
    s8v kr0, kr1;
    {
        const unsigned short* src = k + (size_t)srow * 64 + scs;
        s8v a0 = *(const s8v*)src, a1 = *(const s8v*)(src + 8);
        lds_wr16(kT[0], srow, scb, a0);
        lds_wr16(kT[0], srow, scb + 16, a1);
        const unsigned short* src1 = k + (size_t)(64 + srow) * 64 + scs;
        kr0 = *(const s8v*)src1; kr1 = *(const s8v*)(src1 + 8);
    }
    __syncthreads();
    for (int kt = 0; kt < 32; kt++) {
        const unsigned short* kcur = kT[kt & 1];
        unsigned short* knxt = (unsigned short*)kT[(kt & 1) ^ 1];
        if (kt < 31) {
            lds_wr16(knxt, srow, scb, kr0);
            lds_wr16(knxt, srow, scb + 16, kr1);
        }
        if (kt < 30) {
            const unsigned short* src = k + (size_t)((kt + 2) * 64 + srow) * 64 + scs;
            kr0 = *(const s8v*)src; kr1 = *(const s8v*)(src + 8);
        }
        u64 mm[4];
#pragma unroll
        for (int r = 0; r < 4; r++) mm[r] = *(const u64*)(mbits + rowbase + r * 64 + kt * 2);
        f4 cc[4];
        __builtin_amdgcn_s_setprio(1);
#pragma unroll
        for (int t = 0; t < 4; t++) {
            s8v b0 = lds_rd16(kcur, t * 16 + fr, fq * 16);
            s8v b1 = lds_rd16(kcur, t * 16 + fr, 64 + fq * 16);
            f4 c = {0.f, 0.f, 0.f, 0.f};
            c = __builtin_amdgcn_mfma_f32_16x16x32_bf16(aq0, b0, c, 0, 0, 0);
            c = __builtin_amdgcn_mfma_f32_16x16x32_bf16(aq1, b1, c, 0, 0, 0);
            cc[t] = c;
        }
        __builtin_amdgcn_s_setprio(0);
#pragma unroll
        for (int t = 0; t < 4; t++)
#pragma unroll
            for (int r = 0; r < 4; r++)
                cc[t][r] = ((mm[r] >> (t * 16 + fr)) & 1ULL) ? cc[t][r] : NEGV;
#pragma unroll
        for (int r = 0; r < 4; r++) {
            float mx = fmaxf(fmaxf(cc[0][r], cc[1][r]), fmaxf(cc[2][r], cc[3][r]));
            mx = fmaxf(mx, __shfl_xor(mx, 1));
            mx = fmaxf(mx, __shfl_xor(mx, 2));
            mx = fmaxf(mx, __shfl_xor(mx, 4));
            mx = fmaxf(mx, __shfl_xor(mx, 8));
            float mn = fmaxf(m0[r], mx);
            float sm = __expf(cc[0][r] - mn) + __expf(cc[1][r] - mn) +
                       __expf(cc[2][r] - mn) + __expf(cc[3][r] - mn);
            sm += __shfl_xor(sm, 1);
            sm += __shfl_xor(sm, 2);
            sm += __shfl_xor(sm, 4);
            sm += __shfl_xor(sm, 8);
            l0[r] = l0[r] * __expf(m0[r] - mn) + sm;
            m0[r] = mn;
        }
        __syncthreads();
    }
    float li[4];
#pragma unroll
    for (int r = 0; r < 4; r++) li[r] = 1.f / l0[r];

    f4 xacc[4];
#pragma unroll
    for (int ct = 0; ct < 4; ct++) xacc[ct] = (f4){0.f, 0.f, 0.f, 0.f};

    float* attnbase = attn + ((size_t)(bb * 16 + hh)) * S * S;

    // ---- pass 2: recompute, write attention, accumulate PV ----
    s8v vr0, vr1;
    {
        const unsigned short* src = k + (size_t)srow * 64 + scs;
        s8v a0 = *(const s8v*)src, a1 = *(const s8v*)(src + 8);
        const unsigned short* vs = vt + (size_t)srow * 2048 + scs;
        s8v b0 = *(const s8v*)vs, b1 = *(const s8v*)(vs + 8);
        lds_wr16(kT[0], srow, scb, a0);
        lds_wr16(kT[0], srow, scb + 16, a1);
        lds_wr16(vT[0], srow, scb, b0);
        lds_wr16(vT[0], srow, scb + 16, b1);
        const unsigned short* src1 = k + (size_t)(64 + srow) * 64 + scs;
        kr0 = *(const s8v*)src1; kr1 = *(const s8v*)(src1 + 8);
        const unsigned short* vs1 = vt + (size_t)srow * 2048 + 64 + scs;
        vr0 = *(const s8v*)vs1; vr1 = *(const s8v*)(vs1 + 8);
    }
    __syncthreads();
    for (int kt = 0; kt < 32; kt++) {
        const int sk0 = kt * 64;
        const unsigned short* kcur = kT[kt & 1];
        const unsigned short* vcur = vT[kt & 1];
        unsigned short* knxt = (unsigned short*)kT[(kt & 1) ^ 1];
        unsigned short* vnxt = (unsigned short*)vT[(kt & 1) ^ 1];
        if (kt < 31) {
            lds_wr16(knxt, srow, scb, kr0);
            lds_wr16(knxt, srow, scb + 16, kr1);
            lds_wr16(vnxt, srow, scb, vr0);
            lds_wr16(vnxt, srow, scb + 16, vr1);
        }
        if (kt < 30) {
            const unsigned short* src = k + (size_t)(sk0 + 128 + srow) * 64 + scs;
            kr0 = *(const s8v*)src; kr1 = *(const s8v*)(src + 8);
            const unsigned short* vs = vt + (size_t)srow * 2048 + sk0 + 128 + scs;
            vr0 = *(const s8v*)vs; vr1 = *(const s8v*)(vs + 8);
        }
        u64 mm[4];
#pragma unroll
        for (int r = 0; r < 4; r++) mm[r] = *(const u64*)(mbits + rowbase + r * 64 + kt * 2);
        f4 cc[4];
        __builtin_amdgcn_s_setprio(1);
#pragma unroll
        for (int t = 0; t < 4; t++) {
            s8v b0 = lds_rd16(kcur, t * 16 + fr, fq * 16);
            s8v b1 = lds_rd16(kcur, t * 16 + fr, 64 + fq * 16);
            f4 c = {0.f, 0.f, 0.f, 0.f};
            c = __builtin_amdgcn_mfma_f32_16x16x32_bf16(aq0, b0, c, 0, 0, 0);
            c = __builtin_amdgcn_mfma_f32_16x16x32_bf16(aq1, b1, c, 0, 0, 0);
            cc[t] = c;
        }
        __builtin_amdgcn_s_setprio(0);
#pragma unroll
        for (int t = 0; t < 4; t++) {
#pragma unroll
            for (int r = 0; r < 4; r++) {
                float ev = ((mm[r] >> (t * 16 + fr)) & 1ULL) ? cc[t][r] : NEGV;
                float p = __expf(ev - m0[r]) * li[r];
                int sq = sqbase + r;
                __builtin_nontemporal_store(p, attnbase + (size_t)sq * S + sk0 + t * 16 + fr);
                int prow = wv * 16 + fq * 4 + r;  // per-wave private rows
                *(unsigned short*)((char*)pS + swz_a(prow, (t * 16 + fr) * 2)) = f2b(p);
            }
        }
        // PV: pS rows are same-wave (in-order DS), vcur stable until end-of-iter barrier
        __builtin_amdgcn_s_setprio(1);
#pragma unroll
        for (int s2 = 0; s2 < 2; s2++) {
            s8v ap = lds_rd16(pS, wv * 16 + fr, s2 * 64 + fq * 16);
#pragma unroll
            for (int ct = 0; ct < 4; ct++) {
                s8v bv = lds_rd16(vcur, ct * 16 + fr, s2 * 64 + fq * 16);
                xacc[ct] = __builtin_amdgcn_mfma_f32_16x16x32_bf16(ap, bv, xacc[ct], 0, 0, 0);
            }
        }
        __builtin_amdgcn_s_setprio(0);
        __syncthreads();
    }
#pragma unroll
    for (int ct = 0; ct < 4; ct++) {
#pragma unroll
        for (int r = 0; r < 4; r++) {
            int sq = sqbase + r;
            xh[((size_t)bb * 2048 + sq) * 1024 + hh * 64 + ct * 16 + fr] = f2b(xacc[ct][r]);
        }
    }
}

extern "C" void kernel_launch(void* const* d_in, const int* in_sizes, int n_in,
                              void* d_out, int out_size, void* d_ws, size_t ws_size,
                              hipStream_t stream) {
    const float* query = (const float*)d_in[0];
    const float* key = (const float*)d_in[1];
    const float* value = (const float*)d_in[2];
    const int* mask = (const int*)d_in[3];
    const float* Wq = (const float*)d_in[4];
    const float* bq = (const float*)d_in[5];
    const float* Wk = (const float*)d_in[6];
    const float* bk = (const float*)d_in[7];
    const float* Wv = (const float*)d_in[8];
    const float* bv = (const float*)d_in[9];
    const float* Wo = (const float*)d_in[10];
    const float* bo = (const float*)d_in[11];

    char* ws = (char*)d_ws;
    const size_t HSZ = 16777216;  // bf16 [4,16,2048,64] bytes
    unsigned short* q_h = (unsigned short*)(ws);
    unsigned short* k_h = (unsigned short*)(ws + HSZ);
    unsigned short* vt_h = (unsigned short*)(ws + 2 * HSZ);  // [B,NH,HD,S]
    unsigned short* x_h = (unsigned short*)(ws + 3 * HSZ);   // doubles as bf16-activation scratch
    unsigned int* mbits = (unsigned int*)(ws + 4 * HSZ);
    unsigned short* wqb = (unsigned short*)(ws + 4 * HSZ + 2097152);
    unsigned short* wkb = (unsigned short*)(ws + 4 * HSZ + 2 * 2097152);
    unsigned short* wvb = (unsigned short*)(ws + 4 * HSZ + 3 * 2097152);
    unsigned short* wob = (unsigned short*)(ws + 4 * HSZ + 4 * 2097152);

    float* outp = (float*)d_out;
    float* attnp = outp + 8388608;

    pack_mask_kernel<<<65536, 256, 0, stream>>>(mask, mbits);
    cvt_w_kernel<<<dim3(1024, 4), 256, 0, stream>>>(Wq, Wk, Wv, Wo, wqb, wkb, wvb, wob);
    // x_h is free until attn writes it -> reuse as bf16 activation staging
    cvt_a_kernel<<<8192, 256, 0, stream>>>(query, x_h);
    gemm_kernel<0><<<dim3(64, 8), 256, 0, stream>>>(x_h, wqb, bq, q_h, 0.125f);
    cvt_a_kernel<<<8192, 256, 0, stream>>>(key, x_h);
    gemm_kernel<0><<<dim3(64, 8), 256, 0, stream>>>(x_h, wkb, bk, k_h, 1.0f);
    cvt_a_kernel<<<8192, 256, 0, stream>>>(value, x_h);
    gemm_kernel<2><<<dim3(64, 8), 256, 0, stream>>>(x_h, wvb, bv, vt_h, 1.0f);
    attn_kernel<<<dim3(32, 16, 4), 256, 0, stream>>>(q_h, k_h, vt_h, mbits, attnp, x_h);
    gemm_kernel<1><<<dim3(64, 8), 256, 0, stream>>>(x_h, wob, bo, outp, 1.0f);
}

// Round 3
// 1496.635 us; speedup vs baseline: 1.2804x; 1.0247x over previous
//
#include <hip/hip_runtime.h>

typedef float f4 __attribute__((ext_vector_type(4)));
typedef short s8v __attribute__((ext_vector_type(8)));
typedef unsigned short us4 __attribute__((ext_vector_type(4)));
typedef unsigned long long u64;

#define NEGV -1.0e10f

__device__ __forceinline__ unsigned short f2b(float f) {
    unsigned int u = __builtin_bit_cast(unsigned int, f);
    unsigned int r = u + 0x7fffu + ((u >> 16) & 1u);
    return (unsigned short)(r >> 16);
}

// XOR swizzle for 128B-row LDS tiles (both-sides-or-neither)
__device__ __forceinline__ int swz_a(int row, int cb) {
    return (row * 128 + cb) ^ ((row & 7) << 4);
}
__device__ __forceinline__ void lds_wr16(unsigned short* b, int row, int cb, s8v v) {
    *(s8v*)((char*)b + swz_a(row, cb)) = v;
}
__device__ __forceinline__ void lds_wr8(unsigned short* b, int row, int cb, us4 v) {
    *(us4*)((char*)b + swz_a(row, cb)) = v;
}
__device__ __forceinline__ s8v lds_rd16(const unsigned short* b, int row, int cb) {
    return *(const s8v*)((const char*)b + swz_a(row, cb));
}

__device__ __forceinline__ void gll16(const void* g, void* l) {
    __builtin_amdgcn_global_load_lds((const __attribute__((address_space(1))) void*)g,
                                     (__attribute__((address_space(3))) void*)l, 16, 0, 0);
}

// ---------------- mask packing: ballot, coalesced ----------------
__global__ __launch_bounds__(256) void pack_mask_kernel(const int* __restrict__ mask,
                                                        unsigned int* __restrict__ bits) {
    int i = blockIdx.x * 256 + threadIdx.x;  // one int per thread, 16.8M total
    u64 b = __ballot(mask[i] != 0);
    if ((threadIdx.x & 63) == 0) *(u64*)(bits + (i >> 5)) = b;
}

// ---------------- fp32 -> bf16 vectorized converts ----------------
__global__ __launch_bounds__(256) void cvt_w_kernel(
    const float* __restrict__ w0, const float* __restrict__ w1,
    const float* __restrict__ w2, const float* __restrict__ w3,
    unsigned short* __restrict__ o0, unsigned short* __restrict__ o1,
    unsigned short* __restrict__ o2, unsigned short* __restrict__ o3) {
    const float* src;
    unsigned short* dst;
    switch (blockIdx.y) {
        case 0: src = w0; dst = o0; break;
        case 1: src = w1; dst = o1; break;
        case 2: src = w2; dst = o2; break;
        default: src = w3; dst = o3; break;
    }
    int i = (blockIdx.x * blockDim.x + threadIdx.x) * 4;
    f4 v = *(const f4*)(src + i);
    us4 t;
    t.x = f2b(v.x); t.y = f2b(v.y); t.z = f2b(v.z); t.w = f2b(v.w);
    *(us4*)&dst[i] = t;
}

__global__ __launch_bounds__(256) void cvt_a_kernel(const float* __restrict__ src,
                                                    unsigned short* __restrict__ dst) {
    int i = (blockIdx.x * 256 + threadIdx.x) * 4;
    f4 v = *(const f4*)(src + i);
    us4 t;
    t.x = f2b(v.x); t.y = f2b(v.y); t.z = f2b(v.z); t.w = f2b(v.w);
    *(us4*)&dst[i] = t;
}

// ---------------- GEMM m97-structure: C[M,N] = A[M,K] @ W[N,K]^T + bias ----------------
// A bf16. OUTM==0: bf16 out [B,NH,S,HD] * scale; OUTM==1: fp32 flat [M,N];
// OUTM==2: bf16 out transposed [B,NH,HD,S] (for V)
template <int OUTM>
__global__ __launch_bounds__(256) void gemm_kernel(const unsigned short* __restrict__ A,
                                                   const unsigned short* __restrict__ Bw,
                                                   const float* __restrict__ bias,
                                                   void* __restrict__ Outp, float scale) {
    constexpr int K = 1024;
    __shared__ unsigned short As[128 * 32];
    __shared__ unsigned short Bs[128 * 32];
    const int tid = threadIdx.x;
    const int lane = tid & 63;
    const int wv = tid >> 6;
    const int wrow = (wv >> 1) * 64, wcol = (wv & 1) * 64;
    const int fr = lane & 15, fq = lane >> 4;
    const int bm = blockIdx.x * 128, bn = blockIdx.y * 128;

    f4 zero = {0.f, 0.f, 0.f, 0.f};
    f4 acc[4][4];
#pragma unroll
    for (int a = 0; a < 4; a++)
#pragma unroll
        for (int b2 = 0; b2 < 4; b2++) acc[a][b2] = zero;

    for (int k0 = 0; k0 < K; k0 += 32) {
        // global -> LDS direct, 16B/lane, linear LDS (gll writes wave-uniform base + lane*16)
#pragma unroll
        for (int c = 0; c < 2; c++) {
            int off = wv * 2048 + c * 1024 + lane * 16;  // byte offset within 8KB tile
            int row = off >> 6;                          // 64B per row (32 bf16)
            int col = (off & 63) >> 1;                   // shorts
            gll16(A + (size_t)(bm + row) * K + k0 + col, (char*)As + wv * 2048 + c * 1024);
            gll16(Bw + (size_t)(bn + row) * K + k0 + col, (char*)Bs + wv * 2048 + c * 1024);
        }
        __syncthreads();  // drains vmcnt(0): gll complete
        s8v af[4], bf[4];
#pragma unroll
        for (int rt = 0; rt < 4; rt++) af[rt] = *(const s8v*)&As[(wrow + rt * 16 + fr) * 32 + fq * 8];
#pragma unroll
        for (int ct = 0; ct < 4; ct++) bf[ct] = *(const s8v*)&Bs[(wcol + ct * 16 + fr) * 32 + fq * 8];
#pragma unroll
        for (int rt = 0; rt < 4; rt++)
#pragma unroll
            for (int ct = 0; ct < 4; ct++)
                acc[rt][ct] = __builtin_amdgcn_mfma_f32_16x16x32_bf16(af[rt], bf[ct], acc[rt][ct], 0, 0, 0);
        __syncthreads();
    }
#pragma unroll
    for (int rt = 0; rt < 4; rt++) {
#pragma unroll
        for (int ct = 0; ct < 4; ct++) {
            int j = bn + wcol + ct * 16 + fr;
            float bj = bias[j];
#pragma unroll
            for (int r = 0; r < 4; r++) {
                int i = bm + wrow + rt * 16 + fq * 4 + r;
                float v = (acc[rt][ct][r] + bj) * scale;
                if (OUTM == 0) {
                    int batch = i >> 11, s = i & 2047, hh = j >> 6, d = j & 63;
                    ((unsigned short*)Outp)[(((size_t)(batch * 16 + hh) * 2048 + s) * 64) + d] = f2b(v);
                } else if (OUTM == 1) {
                    ((float*)Outp)[(size_t)i * 1024 + j] = v;
                } else {
                    int batch = i >> 11, s = i & 2047, hh = j >> 6, d = j & 63;
                    ((unsigned short*)Outp)[(((size_t)(batch * 16 + hh) * 64 + d) * 2048) + s] = f2b(v);
                }
            }
        }
    }
}

// ---------------- fused two-pass attention, per (qtile64, head, batch) ----------------
// Swapped QK^T: c = mfma(K_frag, Q_frag) => lane (fq,fr) holds P[q=fr][k=t*16+fq*4+r]
// -> per-lane row softmax, vectorized attention stores, packed pS writes.
// V input pre-transposed: vth is [B,NH,HD,S]. Double-buffered K/V tiles, 1 barrier/iter.
__global__ __launch_bounds__(256) void attn_kernel(const unsigned short* __restrict__ qh,
                                                   const unsigned short* __restrict__ kh,
                                                   const unsigned short* __restrict__ vth,
                                                   const unsigned int* __restrict__ mbits,
                                                   float* __restrict__ attn,
                                                   unsigned short* __restrict__ xh) {
    const int S = 2048;
    const int qt = blockIdx.x, hh = blockIdx.y, bb = blockIdx.z;
    const int tid = threadIdx.x, lane = tid & 63, wv = tid >> 6;
    const int fr = lane & 15, fq = lane >> 4;
    __shared__ unsigned short kT[2][64 * 64];  // [k][d], XOR-swizzled, double-buffered
    __shared__ unsigned short vT[2][64 * 64];  // [d][k], XOR-swizzled, double-buffered
    __shared__ unsigned short pS[64 * 64];     // [q][k], per-wave private rows
    size_t hoff = ((size_t)(bb * 16 + hh)) * S * 64;
    const unsigned short* q = qh + hoff;
    const unsigned short* k = kh + hoff;
    const unsigned short* vt = vth + hoff;  // row stride S (d-major)
    const int srow = tid >> 2;
    const int scb = (tid & 3) * 32;  // byte col of first 16B chunk
    const int scs = scb >> 1;        // in shorts

    // ---- Q tile -> LDS (borrow pS) -> persistent B-operand frags ----
    {
        const unsigned short* src = q + (size_t)(qt * 64 + srow) * 64 + scs;
        lds_wr16(pS, srow, scb, *(const s8v*)src);
        lds_wr16(pS, srow, scb + 16, *(const s8v*)(src + 8));
    }
    __syncthreads();
    s8v aq0 = lds_rd16(pS, wv * 16 + fr, fq * 16);        // Q[wv*16+fr][d=fq*8..]
    s8v aq1 = lds_rd16(pS, wv * 16 + fr, 64 + fq * 16);   // Q[wv*16+fr][32+fq*8..]
    // pS next written in pass 2, many barriers away -> no extra barrier

    const int qloc = qt * 64 + wv * 16 + fr;              // this lane's q-row (softmax role)
    const size_t mrow = (size_t)(bb * 2048 + qloc) * 64;  // mask u32-word base of q-row
    float m0 = -__builtin_huge_valf(), l0 = 0.f;

    // ---- pass 1: row max + sumexp ----
    s8v kr0, kr1;
    {
        const unsigned short* src = k + (size_t)srow * 64 + scs;
        s8v a0 = *(const s8v*)src, a1 = *(const s8v*)(src + 8);
        lds_wr16(kT[0], srow, scb, a0);
        lds_wr16(kT[0], srow, scb + 16, a1);
        const unsigned short* src1 = k + (size_t)(64 + srow) * 64 + scs;
        kr0 = *(const s8v*)src1; kr1 = *(const s8v*)(src1 + 8);
    }
    __syncthreads();
    for (int kt = 0; kt < 32; kt++) {
        const unsigned short* kcur = kT[kt & 1];
        unsigned short* knxt = (unsigned short*)kT[(kt & 1) ^ 1];
        if (kt < 31) {
            lds_wr16(knxt, srow, scb, kr0);
            lds_wr16(knxt, srow, scb + 16, kr1);
        }
        if (kt < 30) {
            const unsigned short* src = k + (size_t)((kt + 2) * 64 + srow) * 64 + scs;
            kr0 = *(const s8v*)src; kr1 = *(const s8v*)(src + 8);
        }
        u64 mm = *(const u64*)(mbits + mrow + kt * 2);
        f4 cc[4];
        __builtin_amdgcn_s_setprio(1);
#pragma unroll
        for (int t = 0; t < 4; t++) {
            s8v b0 = lds_rd16(kcur, t * 16 + fr, fq * 16);
            s8v b1 = lds_rd16(kcur, t * 16 + fr, 64 + fq * 16);
            f4 c = {0.f, 0.f, 0.f, 0.f};
            c = __builtin_amdgcn_mfma_f32_16x16x32_bf16(b0, aq0, c, 0, 0, 0);  // swapped: C[k][q]
            c = __builtin_amdgcn_mfma_f32_16x16x32_bf16(b1, aq1, c, 0, 0, 0);
            cc[t] = c;
        }
        __builtin_amdgcn_s_setprio(0);
#pragma unroll
        for (int t = 0; t < 4; t++)
#pragma unroll
            for (int r = 0; r < 4; r++)
                cc[t][r] = ((mm >> (t * 16 + fq * 4 + r)) & 1ULL) ? cc[t][r] : NEGV;
        // per-lane row reduce (one q-row per lane) + cross-fq (lanes ^16, ^32)
        float mx = -__builtin_huge_valf();
#pragma unroll
        for (int t = 0; t < 4; t++)
            mx = fmaxf(mx, fmaxf(fmaxf(cc[t][0], cc[t][1]), fmaxf(cc[t][2], cc[t][3])));
        mx = fmaxf(mx, __shfl_xor(mx, 16));
        mx = fmaxf(mx, __shfl_xor(mx, 32));
        float mn = fmaxf(m0, mx);
        float sm = 0.f;
#pragma unroll
        for (int t = 0; t < 4; t++)
#pragma unroll
            for (int r = 0; r < 4; r++) sm += __expf(cc[t][r] - mn);
        sm += __shfl_xor(sm, 16);
        sm += __shfl_xor(sm, 32);
        l0 = l0 * __expf(m0 - mn) + sm;
        m0 = mn;
        __syncthreads();
    }
    const float li = 1.f / l0;

    f4 xacc[4];
#pragma unroll
    for (int ct = 0; ct < 4; ct++) xacc[ct] = (f4){0.f, 0.f, 0.f, 0.f};

    float* attnrow = attn + ((size_t)(bb * 16 + hh)) * S * S + (size_t)qloc * S;

    // ---- pass 2: recompute, write attention (f4 nontemporal), packed pS, PV ----
    s8v vr0, vr1;
    {
        const unsigned short* src = k + (size_t)srow * 64 + scs;
        s8v a0 = *(const s8v*)src, a1 = *(const s8v*)(src + 8);
        const unsigned short* vs = vt + (size_t)srow * 2048 + scs;
        s8v b0 = *(const s8v*)vs, b1 = *(const s8v*)(vs + 8);
        lds_wr16(kT[0], srow, scb, a0);
        lds_wr16(kT[0], srow, scb + 16, a1);
        lds_wr16(vT[0], srow, scb, b0);
        lds_wr16(vT[0], srow, scb + 16, b1);
        const unsigned short* src1 = k + (size_t)(64 + srow) * 64 + scs;
        kr0 = *(const s8v*)src1; kr1 = *(const s8v*)(src1 + 8);
        const unsigned short* vs1 = vt + (size_t)srow * 2048 + 64 + scs;
        vr0 = *(const s8v*)vs1; vr1 = *(const s8v*)(vs1 + 8);
    }
    __syncthreads();
    for (int kt = 0; kt < 32; kt++) {
        const int sk0 = kt * 64;
        const unsigned short* kcur = kT[kt & 1];
        const unsigned short* vcur = vT[kt & 1];
        unsigned short* knxt = (unsigned short*)kT[(kt & 1) ^ 1];
        unsigned short* vnxt = (unsigned short*)vT[(kt & 1) ^ 1];
        if (kt < 31) {
            lds_wr16(knxt, srow, scb, kr0);
            lds_wr16(knxt, srow, scb + 16, kr1);
            lds_wr16(vnxt, srow, scb, vr0);
            lds_wr16(vnxt, srow, scb + 16, vr1);
        }
        if (kt < 30) {
            const unsigned short* src = k + (size_t)(sk0 + 128 + srow) * 64 + scs;
            kr0 = *(const s8v*)src; kr1 = *(const s8v*)(src + 8);
            const unsigned short* vs = vt + (size_t)srow * 2048 + sk0 + 128 + scs;
            vr0 = *(const s8v*)vs; vr1 = *(const s8v*)(vs + 8);
        }
        u64 mm = *(const u64*)(mbits + mrow + kt * 2);
        f4 cc[4];
        __builtin_amdgcn_s_setprio(1);
#pragma unroll
        for (int t = 0; t < 4; t++) {
            s8v b0 = lds_rd16(kcur, t * 16 + fr, fq * 16);
            s8v b1 = lds_rd16(kcur, t * 16 + fr, 64 + fq * 16);
            f4 c = {0.f, 0.f, 0.f, 0.f};
            c = __builtin_amdgcn_mfma_f32_16x16x32_bf16(b0, aq0, c, 0, 0, 0);
            c = __builtin_amdgcn_mfma_f32_16x16x32_bf16(b1, aq1, c, 0, 0, 0);
            cc[t] = c;
        }
        __builtin_amdgcn_s_setprio(0);
#pragma unroll
        for (int t = 0; t < 4; t++) {
            f4 pv;
            us4 pk;
#pragma unroll
            for (int r = 0; r < 4; r++) {
                float ev = ((mm >> (t * 16 + fq * 4 + r)) & 1ULL) ? cc[t][r] : NEGV;
                float p = __expf(ev - m0) * li;
                pv[r] = p;
                pk[r] = f2b(p);
            }
            __builtin_nontemporal_store(pv, (f4*)(attnrow + sk0 + t * 16 + fq * 4));
            lds_wr8(pS, wv * 16 + fr, t * 32 + fq * 8, pk);  // P[q=fr][k chunk], packed
        }
        // PV: pS rows are same-wave (in-order DS), vcur stable until end-of-iter barrier
        __builtin_amdgcn_s_setprio(1);
#pragma unroll
        for (int s2 = 0; s2 < 2; s2++) {
            s8v ap = lds_rd16(pS, wv * 16 + fr, s2 * 64 + fq * 16);
#pragma unroll
            for (int ct = 0; ct < 4; ct++) {
                s8v bv = lds_rd16(vcur, ct * 16 + fr, s2 * 64 + fq * 16);
                xacc[ct] = __builtin_amdgcn_mfma_f32_16x16x32_bf16(ap, bv, xacc[ct], 0, 0, 0);
            }
        }
        __builtin_amdgcn_s_setprio(0);
        __syncthreads();
    }
    const int sqbase = qt * 64 + wv * 16 + fq * 4;  // PV C-layout rows
#pragma unroll
    for (int ct = 0; ct < 4; ct++) {
#pragma unroll
        for (int r = 0; r < 4; r++) {
            int sq = sqbase + r;
            xh[((size_t)bb * 2048 + sq) * 1024 + hh * 64 + ct * 16 + fr] = f2b(xacc[ct][r]);
        }
    }
}

extern "C" void kernel_launch(void* const* d_in, const int* in_sizes, int n_in,
                              void* d_out, int out_size, void* d_ws, size_t ws_size,
                              hipStream_t stream) {
    const float* query = (const float*)d_in[0];
    const float* key = (const float*)d_in[1];
    const float* value = (const float*)d_in[2];
    const int* mask = (const int*)d_in[3];
    const float* Wq = (const float*)d_in[4];
    const float* bq = (const float*)d_in[5];
    const float* Wk = (const float*)d_in[6];
    const float* bk = (const float*)d_in[7];
    const float* Wv = (const float*)d_in[8];
    const float* bv = (const float*)d_in[9];
    const float* Wo = (const float*)d_in[10];
    const float* bo = (const float*)d_in[11];

    char* ws = (char*)d_ws;
    const size_t HSZ = 16777216;  // bf16 [4,16,2048,64] bytes
    unsigned short* q_h = (unsigned short*)(ws);
    unsigned short* k_h = (unsigned short*)(ws + HSZ);
    unsigned short* vt_h = (unsigned short*)(ws + 2 * HSZ);  // [B,NH,HD,S]
    unsigned short* x_h = (unsigned short*)(ws + 3 * HSZ);   // doubles as bf16-activation scratch
    unsigned int* mbits = (unsigned int*)(ws + 4 * HSZ);
    unsigned short* wqb = (unsigned short*)(ws + 4 * HSZ + 2097152);
    unsigned short* wkb = (unsigned short*)(ws + 4 * HSZ + 2 * 2097152);
    unsigned short* wvb = (unsigned short*)(ws + 4 * HSZ + 3 * 2097152);
    unsigned short* wob = (unsigned short*)(ws + 4 * HSZ + 4 * 2097152);

    float* outp = (float*)d_out;
    float* attnp = outp + 8388608;

    pack_mask_kernel<<<65536, 256, 0, stream>>>(mask, mbits);
    cvt_w_kernel<<<dim3(1024, 4), 256, 0, stream>>>(Wq, Wk, Wv, Wo, wqb, wkb, wvb, wob);
    // x_h is free until attn writes it -> reuse as bf16 activation staging
    cvt_a_kernel<<<8192, 256, 0, stream>>>(query, x_h);
    gemm_kernel<0><<<dim3(64, 8), 256, 0, stream>>>(x_h, wqb, bq, q_h, 0.125f);
    cvt_a_kernel<<<8192, 256, 0, stream>>>(key, x_h);
    gemm_kernel<0><<<dim3(64, 8), 256, 0, stream>>>(x_h, wkb, bk, k_h, 1.0f);
    cvt_a_kernel<<<8192, 256, 0, stream>>>(value, x_h);
    gemm_kernel<2><<<dim3(64, 8), 256, 0, stream>>>(x_h, wvb, bv, vt_h, 1.0f);
    attn_kernel<<<dim3(32, 16, 4), 256, 0, stream>>>(q_h, k_h, vt_h, mbits, attnp, x_h);
    gemm_kernel<1><<<dim3(64, 8), 256, 0, stream>>>(x_h, wob, bo, outp, 1.0f);
}